// Round 9
// baseline (142.183 us; speedup 1.0000x reference)
//
#include <hip/hip_runtime.h>
#include <cstdint>

#define B_ 16
#define N_ 2048
#define D_ 256
#define EPS_ 1e-9f

#define AS1 __attribute__((address_space(1)))
#define AS3 __attribute__((address_space(3)))

typedef float f4 __attribute__((ext_vector_type(4)));
typedef float f16v __attribute__((ext_vector_type(16)));
typedef int v8i __attribute__((ext_vector_type(8)));

__device__ float blockReduceSum(float x, float* red){
  int tid = threadIdx.x;
  red[tid] = x; __syncthreads();
  #pragma unroll
  for (int off = 128; off > 0; off >>= 1){
    if (tid < off) red[tid] += red[tid + off];
    __syncthreads();
  }
  float r = red[0]; __syncthreads();
  return r;
}

// fp32 norm + fp8(e4m3) conversion; 4 rows/wave, 16 rows/block (one batch/block).
// Emits race-free per-block partials Ppart/npart for tail's fast path.
// Also inits cost/currency/dmin/out (no separate memset dispatch).
__global__ __launch_bounds__(256) void prep_kernel(
    const float* __restrict__ preds, const float* __restrict__ labels,
    unsigned char* __restrict__ pa8, unsigned char* __restrict__ pb8,
    float* __restrict__ pn, float* __restrict__ ln,
    float* __restrict__ cost, float* __restrict__ currency,
    int* __restrict__ dmin, float* __restrict__ Ppart,
    float* __restrict__ npart, float* __restrict__ out){
  int s = blockIdx.y;
  int tid = threadIdx.x;
  if (s == 0){
    int i = blockIdx.x * 256 + tid;
    if (i < B_ * N_){ cost[i] = 1.f; currency[i] = 1.f; }
    if (i < B_) dmin[i] = 0x7f7fffff;  // FLT_MAX bits
    if (i == 0) out[0] = 0.f;
  }
  const float* src = s ? labels : preds;
  unsigned char* dst = s ? pb8 : pa8;
  float* norms = s ? ln : pn;
  int w = tid >> 6, lane = tid & 63;
  size_t row0 = (size_t)blockIdx.x * 16 + (size_t)w * 4;
  float4 v[4];
  #pragma unroll
  for (int q = 0; q < 4; q++)
    v[q] = ((const float4*)(src + (row0 + q) * D_))[lane];
  __shared__ f4 part[4][64];
  __shared__ float nred[4];
  f4 s4;
  s4[0] = v[0].x + v[1].x + v[2].x + v[3].x;
  s4[1] = v[0].y + v[1].y + v[2].y + v[3].y;
  s4[2] = v[0].z + v[1].z + v[2].z + v[3].z;
  s4[3] = v[0].w + v[1].w + v[2].w + v[3].w;
  float nsum = 0.f;
  #pragma unroll
  for (int q = 0; q < 4; q++){
    float sum = v[q].x*v[q].x + v[q].y*v[q].y + v[q].z*v[q].z + v[q].w*v[q].w;
    #pragma unroll
    for (int off = 32; off >= 1; off >>= 1) sum += __shfl_xor(sum, off);
    if (lane == 0){ norms[row0 + q] = sum; nsum += sum; }
    int pk = 0;
    pk = __builtin_amdgcn_cvt_pk_fp8_f32(v[q].x, v[q].y, pk, false); // bytes 0,1
    pk = __builtin_amdgcn_cvt_pk_fp8_f32(v[q].z, v[q].w, pk, true);  // bytes 2,3
    ((unsigned int*)(dst + (row0 + q) * D_))[lane] = (unsigned int)pk;
  }
  part[w][lane] = s4;
  if (lane == 0) nred[w] = nsum;
  __syncthreads();
  if (tid < 64){
    f4 t = part[0][tid];
    #pragma unroll
    for (int q = 1; q < 4; q++){
      t[0] += part[q][tid][0]; t[1] += part[q][tid][1];
      t[2] += part[q][tid][2]; t[3] += part[q][tid][3];
    }
    *(f4*)(Ppart + ((size_t)s * 2048 + blockIdx.x) * 256 + tid * 4) = t;
  }
  if (tid == 0)
    npart[s * 2048 + blockIdx.x] = nred[0] + nred[1] + nred[2] + nred[3];
}

// d[b][n][m] = pn[n] + ln[m] - 2*dot via MX-SCALED FP8 MFMA; NO stores — only
// per-batch min. Round-20: DIAGNOSTIC build. R8 proved co-residency is a null
// and the cycle model (MFMA 7.3 + LDS 5 + epi 2 + prologue 1.5 ~= 13us) fails
// to explain the ~24us measured — a 2.4x unexplained residual after three
// blind structural edits. gemm has never produced a counter row (41us harness
// poison fills crowd top-5). This build is the best structure (R5: 64x64 wave
// tile, panel-resident Bs 64K + As 2x32K full-K stripe dbuf, bfr reg-cache,
// MX 32x32x64 scales=1.0) with the K-loop run TWICE internally (16 steps,
// stripe = step&7, prefetch (step+1)&7 wraps; dead final prefetch harmless;
// atomicMin idempotent -> bitwise-identical dmin). gemm_dur ~45us -> top-5 ->
// first real MfmaUtil/VALUBusy/Occupancy/BANK_CONFLICT/FETCH/WRITE row.
// Next round: revert REP and apply the fix the counters indicate.
// gemm feeds ONLY dmin's skip certificate (guard 16 covers fp8 quant error).
__global__ __launch_bounds__(512, 2) void gemm_minmax(
    const unsigned char* __restrict__ pa, const unsigned char* __restrict__ pbm,
    const float* __restrict__ pn, const float* __restrict__ ln,
    int* __restrict__ dmin)
{
  int lid = blockIdx.x;              // 256 blocks, round-robin over 8 XCDs
  int xcd = lid & 7;
  int l = lid >> 3;                  // 0..31 sequential per XCD
  int b = 2 * xcd + (l >> 4);        // 2 batches per XCD
  int p = l & 15;                    // 8 tn-panels x 2 tm-halves
  int tn = (p & 7) * 256;
  int tmb = (p >> 3) * 1024;         // 8 stripes of 128 rows each
  const unsigned char* A  = pa  + (size_t)b * N_ * D_;
  const unsigned char* Bm = pbm + (size_t)b * N_ * D_;
  __shared__ __align__(16) unsigned char Bs[256 * 256];     // 64 KB, resident
  __shared__ __align__(16) unsigned char As[2][128 * 256];  // 2 x 32 KB dbuf
  __shared__ float minred[8];
  int tid = threadIdx.x, lane = tid & 63, w = tid >> 6;
  int wm = (w >> 2) * 64, wn = (w & 3) * 64;   // 2m x 4n of 64x64 wave tiles
  int l31 = lane & 31, half = lane >> 5;
  int rB = lane >> 4, cB = lane & 15;
  const int SC = 0x7F7F7F7F;         // e8m0 scale 1.0 in every byte

  // ---- stage B panel (256 rows x 256 B) + A stripe 0 (128 rows x 256 B) ----
  #pragma unroll
  for (int q = 0; q < 8; q++){
    int R = q * 32 + w * 4;
    int r = R + rB;
    int gc = cB ^ (r & 7);           // global-side XOR swizzle (involution)
    __builtin_amdgcn_global_load_lds(
        (const AS1 unsigned int*)(const void*)&Bm[(size_t)(tn + r) * D_ + gc * 16],
        (AS3 unsigned int*)(void*)&Bs[R * 256 + lane * 16], 16, 0, 0);
  }
  #pragma unroll
  for (int q = 0; q < 4; q++){
    int R = q * 32 + w * 4;
    int r = R + rB;
    int gc = cB ^ (r & 7);
    __builtin_amdgcn_global_load_lds(
        (const AS1 unsigned int*)(const void*)&A[(size_t)(tmb + r) * D_ + gc * 16],
        (AS3 unsigned int*)(void*)&As[0][R * 256 + lane * 16], 16, 0, 0);
  }

  float lnj[2];
  #pragma unroll
  for (int j = 0; j < 2; j++)
    lnj[j] = ln[(size_t)b * N_ + tn + wn + j * 32 + l31];

  __syncthreads();   // Bs + As[0] resident

  // ---- full-K B fragment cache: 16 x ds_read_b128 -> 64 VGPRs, read once ----
  v8i bfr[2][4];
  #pragma unroll
  for (int j = 0; j < 2; j++){
    int rb = wn + j * 32 + l31;
    #pragma unroll
    for (int kc = 0; kc < 4; kc++){
      int c0 = kc * 4 + half * 2;
      int4 lo = *(const int4*)&Bs[rb * 256 + ((c0 ^ (rb & 7)) * 16)];
      int4 hi = *(const int4*)&Bs[rb * 256 + (((c0 + 1) ^ (rb & 7)) * 16)];
      v8i t;
      t[0] = lo.x; t[1] = lo.y; t[2] = lo.z; t[3] = lo.w;
      t[4] = hi.x; t[5] = hi.y; t[6] = hi.z; t[7] = hi.w;
      bfr[j][kc] = t;
    }
  }

  float mind = 3.4e38f;
  int buf = 0;
  // REP=2 diagnostic: 16 steps over 8 stripes (stripe = step&7). Prefetch
  // (step+1)&7 wraps at rep boundary so rep-1 re-runs identical work; the
  // final prefetch (step 15) is dead but in-bounds and harmless.
  for (int step = 0; step < 16; step++){
    __syncthreads();   // drains As[buf]'s loads (issued one phase ago)
    {
      int stn = (step + 1) & 7;
      #pragma unroll
      for (int q = 0; q < 4; q++){
        int R = q * 32 + w * 4;
        int r = R + rB;
        int gc = cB ^ (r & 7);
        __builtin_amdgcn_global_load_lds(
            (const AS1 unsigned int*)(const void*)&A[(size_t)(tmb + stn * 128 + r) * D_ + gc * 16],
            (AS3 unsigned int*)(void*)&As[buf ^ 1][R * 256 + lane * 16], 16, 0, 0);
      }
    }
    f16v acc[2][2];
    #pragma unroll
    for (int i = 0; i < 2; i++)
      #pragma unroll
      for (int j = 0; j < 2; j++) acc[i][j] = (f16v)0.f;

    #pragma unroll
    for (int kc = 0; kc < 4; kc++){              // k = kc*64 .. +64
      v8i af[2];
      #pragma unroll
      for (int i = 0; i < 2; i++){
        int ra = wm + i * 32 + l31;
        int c0 = kc * 4 + half * 2;
        int4 lo = *(const int4*)&As[buf][ra * 256 + ((c0 ^ (ra & 7)) * 16)];
        int4 hi = *(const int4*)&As[buf][ra * 256 + (((c0 + 1) ^ (ra & 7)) * 16)];
        v8i t;
        t[0] = lo.x; t[1] = lo.y; t[2] = lo.z; t[3] = lo.w;
        t[4] = hi.x; t[5] = hi.y; t[6] = hi.z; t[7] = hi.w;
        af[i] = t;
      }
      #pragma unroll
      for (int i = 0; i < 2; i++)
        #pragma unroll
        for (int j = 0; j < 2; j++)
          acc[i][j] = __builtin_amdgcn_mfma_scale_f32_32x32x64_f8f6f4(
              af[i], bfr[j][kc], acc[i][j], 0, 0, 0, SC, 0, SC);
    }

    // per-stripe epilogue: C/D col = lane&31, row = (reg&3)+8*(reg>>2)+4*half.
    int tm = tmb + (step & 7) * 128;
    #pragma unroll
    for (int i = 0; i < 2; i++){
      float4 pnq[4];
      #pragma unroll
      for (int q = 0; q < 4; q++)
        pnq[q] = *(const float4*)&pn[(size_t)b * N_ + tm + wm + i * 32 + half * 4 + q * 8];
      #pragma unroll
      for (int j = 0; j < 2; j++){
        #pragma unroll
        for (int reg = 0; reg < 16; reg++){
          float pv = ((const float*)&pnq[reg >> 2])[reg & 3];
          float v = pv + lnj[j] - 2.f * acc[i][j][reg];
          mind = fminf(mind, v);
        }
      }
    }
    buf ^= 1;
  }

  #pragma unroll
  for (int off = 32; off >= 1; off >>= 1) mind = fminf(mind, __shfl_xor(mind, off));
  if (lane == 0) minred[w] = mind;
  __syncthreads();
  if (tid == 0){
    float m = minred[0];
    #pragma unroll
    for (int q = 1; q < 8; q++) m = fminf(m, minred[q]);
    atomicMin(&dmin[b], __float_as_int(fmaxf(m, 0.f)));
  }
}

// Merged tail: (1) exact fallback for the 6 negative exp-factors (each skipped
// when provably negligible: B*N^2*dmax*e^{ef*dmin}/EPS < 1e-3 iff
// ef*(dmin-16) < -55; guard 16 covers fp8 dot quantization error, |err|<~8
// at 5-sigma over 4M pairs; gating monotone — if ef=-0.25 skips, all skip);
// (2) the ef=0 term. FAST PATH (all skipped -> cost == currency == 1 exactly):
// alpha = 1/2048 exactly, bw = 1, term = sum|p|^2 + sum|l|^2 - (sum p).(sum l)/1024
// from prep's fp32 partials. SLOW PATH (dead here): exact from fp32 originals.
__global__ __launch_bounds__(256) void tail(
    const float* __restrict__ preds, const float* __restrict__ labels,
    const float* __restrict__ pn, const float* __restrict__ ln,
    float* __restrict__ cost, float* __restrict__ currency,
    const int* __restrict__ dmin, const float* __restrict__ Ppart,
    const float* __restrict__ npart, float* __restrict__ out)
{
  const float EF[6] = {-256.f, -64.f, -16.f, -4.f, -1.f, -0.25f};
  int b = blockIdx.x, tid = threadIdx.x;
  float dm = __int_as_float(dmin[b]);
  __shared__ float red[256];

  if (-0.25f * (dm - 16.f) < -55.f){
    // ---- fast path: all 6 negative iterations certified negligible ----
    float Pc = 0.f, Lc = 0.f;
    for (int k = 0; k < 128; k++){
      Pc += Ppart[((size_t)b * 128 + k) * 256 + tid];
      Lc += Ppart[((size_t)(2048 + b * 128 + k)) * 256 + tid];
    }
    float np = (tid < 128) ? npart[b * 128 + tid] : 0.f;
    float nl = (tid < 128) ? npart[2048 + b * 128 + tid] : 0.f;
    float Spn = blockReduceSum(np, red);
    float Sln = blockReduceSum(nl, red);
    float dot = blockReduceSum(Pc * Lc, red);
    if (tid == 0) atomicAdd(out, Spn + Sln - dot * (1.f / 1024.f));
    return;
  }

  // ---- slow exact path from fp32 originals (not expected to execute) ----
  __shared__ float alpha_l[N_];
  __shared__ float prow[D_];
  const float* A  = preds  + (size_t)b * N_ * D_;
  const float* Bm = labels + (size_t)b * N_ * D_;
  const float* pnb = pn + (size_t)b * N_;
  const float* lnb = ln + (size_t)b * N_;
  float* costb = cost + (size_t)b * N_;
  float* curb  = currency + (size_t)b * N_;
  for (int it = 0; it < 6; it++){
    float ef = EF[it];
    if (ef * (dm - 16.f) < -55.f) continue;
    float cost_c[8], colsum_c[8], bw_c[8], costnew_c[8];
    #pragma unroll
    for (int j = 0; j < 8; j++){ cost_c[j] = costb[j*256+tid]; colsum_c[j] = 0.f; }
    for (int r = 0; r < N_; r++){
      prow[tid] = A[(size_t)r * D_ + tid];
      __syncthreads();
      float s_c[8], rs = 0.f;
      for (int j = 0; j < 8; j++){
        int m = j*256+tid; float dot = 0.f;
        for (int k = 0; k < D_; k++) dot += prow[k] * Bm[(size_t)m * D_ + k];
        float d = pnb[r] + lnb[m] - 2.f*dot;
        float s = __expf(ef * d) * cost_c[j];
        s_c[j] = s; rs += s;
      }
      float tot = blockReduceSum(rs, red);
      float a = curb[r] / (tot + EPS_);
      if (tid == 0) alpha_l[r] = a;
      #pragma unroll
      for (int j = 0; j < 8; j++) colsum_c[j] += s_c[j] * a;
      __syncthreads();
    }
    #pragma unroll
    for (int j = 0; j < 8; j++){
      float cs = colsum_c[j];
      float bw = fminf(cost_c[j] / (cs + EPS_), 1.f);
      bw_c[j] = bw; costnew_c[j] = fmaxf(cost_c[j] - bw*cs, 0.f);
    }
    float contrib = 0.f;
    for (int r = 0; r < N_; r++){
      prow[tid] = A[(size_t)r * D_ + tid];
      __syncthreads();
      float a = alpha_l[r], rbs = 0.f;
      for (int j = 0; j < 8; j++){
        int m = j*256+tid; float dot = 0.f;
        for (int k = 0; k < D_; k++) dot += prow[k] * Bm[(size_t)m * D_ + k];
        float d = pnb[r] + lnb[m] - 2.f*dot;
        float bid = __expf(ef * d) * cost_c[j] * a * bw_c[j];
        rbs += bid; contrib += bid * d;
      }
      float tot = blockReduceSum(rbs, red);
      if (tid == 0) curb[r] = fmaxf(curb[r] - tot, 0.f);
      __syncthreads();
    }
    #pragma unroll
    for (int j = 0; j < 8; j++) costb[j*256+tid] = costnew_c[j];
    float ctot = blockReduceSum(contrib, red);
    if (tid == 0) atomicAdd(out, ctot);
    __syncthreads();
  }
  // ef=0 closed form with the general state (exact):
  float s = 0.f;
  #pragma unroll
  for (int j = 0; j < 8; j++) s += costb[j*256+tid];
  float Sc = blockReduceSum(s, red);
  float sa = 0.f, spn = 0.f;
  #pragma unroll
  for (int j = 0; j < 8; j++){
    int i = j*256+tid;
    float a = curb[i] / (Sc + EPS_);
    alpha_l[i] = a; sa += a; spn += a * pnb[i];
  }
  float Sa  = blockReduceSum(sa, red);
  float Spn = blockReduceSum(spn, red);
  float Pc = 0.f;
  for (int r = 0; r < N_; r++)
    Pc += alpha_l[r] * A[(size_t)r * D_ + tid];
  __syncthreads();
  float sv = 0.f, sln = 0.f;
  #pragma unroll
  for (int j = 0; j < 8; j++){
    int i = j*256+tid;
    float c = costb[i];
    float bw = fminf(c / (c * Sa + EPS_), 1.f);
    float vv = c * bw;
    alpha_l[i] = vv; sv += vv; sln += vv * lnb[i];
  }
  float Sv  = blockReduceSum(sv, red);
  float Sln = blockReduceSum(sln, red);
  float Lc = 0.f;
  for (int m = 0; m < N_; m++)
    Lc += alpha_l[m] * Bm[(size_t)m * D_ + tid];
  float dot = blockReduceSum(Pc * Lc, red);
  if (tid == 0) atomicAdd(out, Spn * Sv + Sa * Sln - 2.f * dot);
}

extern "C" void kernel_launch(void* const* d_in, const int* in_sizes, int n_in,
                              void* d_out, int out_size, void* d_ws, size_t ws_size,
                              hipStream_t stream)
{
  const float* preds  = (const float*)d_in[0];
  const float* labels = (const float*)d_in[1];
  float* out = (float*)d_out;
  char* ws = (char*)d_ws;
  const size_t BN = (size_t)B_ * N_;
  size_t off = 0;
  float* cost     = (float*)(ws + off); off += BN * 4;
  float* currency = (float*)(ws + off); off += BN * 4;
  float* pn       = (float*)(ws + off); off += BN * 4;
  float* ln       = (float*)(ws + off); off += BN * 4;
  int*   dmin     = (int*)(ws + off);   off += 256;
  float* npart    = (float*)(ws + off); off += (size_t)2 * 2048 * 4;
  float* Ppart    = (float*)(ws + off); off += (size_t)2 * 2048 * 256 * 4;
  unsigned char* pa8 = (unsigned char*)(ws + off); off += BN * D_;
  unsigned char* pb8 = (unsigned char*)(ws + off); off += BN * D_;

  prep_kernel<<<dim3((unsigned)(BN / 16), 2), 256, 0, stream>>>(
      preds, labels, pa8, pb8, pn, ln, cost, currency, dmin, Ppart, npart, out);
  gemm_minmax<<<dim3(256), 512, 0, stream>>>(pa8, pb8, pn, ln, dmin);
  tail<<<dim3(B_), 256, 0, stream>>>(preds, labels, pn, ln, cost, currency, dmin,
                                     Ppart, npart, out);
}

// Round 11
// 125.320 us; speedup vs baseline: 1.1346x; 1.1346x over previous
//
#include <hip/hip_runtime.h>
#include <cstdint>

#define B_ 16
#define N_ 2048
#define D_ 256
#define EPS_ 1e-9f

#define AS1 __attribute__((address_space(1)))
#define AS3 __attribute__((address_space(3)))

typedef float f4 __attribute__((ext_vector_type(4)));
typedef float f16v __attribute__((ext_vector_type(16)));
typedef int v8i __attribute__((ext_vector_type(8)));

__device__ float blockReduceSum(float x, float* red){
  int tid = threadIdx.x;
  red[tid] = x; __syncthreads();
  #pragma unroll
  for (int off = 128; off > 0; off >>= 1){
    if (tid < off) red[tid] += red[tid + off];
    __syncthreads();
  }
  float r = red[0]; __syncthreads();
  return r;
}

// fp32 norm + fp8(e4m3) conversion; 4 rows/wave, 16 rows/block (one batch/block).
// Emits race-free per-block partials Ppart/npart for tail's fast path.
// Also inits cost/currency/dmin/out (no separate memset dispatch).
__global__ __launch_bounds__(256) void prep_kernel(
    const float* __restrict__ preds, const float* __restrict__ labels,
    unsigned char* __restrict__ pa8, unsigned char* __restrict__ pb8,
    float* __restrict__ pn, float* __restrict__ ln,
    float* __restrict__ cost, float* __restrict__ currency,
    int* __restrict__ dmin, float* __restrict__ Ppart,
    float* __restrict__ npart, float* __restrict__ out){
  int s = blockIdx.y;
  int tid = threadIdx.x;
  if (s == 0){
    int i = blockIdx.x * 256 + tid;
    if (i < B_ * N_){ cost[i] = 1.f; currency[i] = 1.f; }
    if (i < B_) dmin[i] = 0x7f7fffff;  // FLT_MAX bits
    if (i == 0) out[0] = 0.f;
  }
  const float* src = s ? labels : preds;
  unsigned char* dst = s ? pb8 : pa8;
  float* norms = s ? ln : pn;
  int w = tid >> 6, lane = tid & 63;
  size_t row0 = (size_t)blockIdx.x * 16 + (size_t)w * 4;
  float4 v[4];
  #pragma unroll
  for (int q = 0; q < 4; q++)
    v[q] = ((const float4*)(src + (row0 + q) * D_))[lane];
  __shared__ f4 part[4][64];
  __shared__ float nred[4];
  f4 s4;
  s4[0] = v[0].x + v[1].x + v[2].x + v[3].x;
  s4[1] = v[0].y + v[1].y + v[2].y + v[3].y;
  s4[2] = v[0].z + v[1].z + v[2].z + v[3].z;
  s4[3] = v[0].w + v[1].w + v[2].w + v[3].w;
  float nsum = 0.f;
  #pragma unroll
  for (int q = 0; q < 4; q++){
    float sum = v[q].x*v[q].x + v[q].y*v[q].y + v[q].z*v[q].z + v[q].w*v[q].w;
    #pragma unroll
    for (int off = 32; off >= 1; off >>= 1) sum += __shfl_xor(sum, off);
    if (lane == 0){ norms[row0 + q] = sum; nsum += sum; }
    int pk = 0;
    pk = __builtin_amdgcn_cvt_pk_fp8_f32(v[q].x, v[q].y, pk, false); // bytes 0,1
    pk = __builtin_amdgcn_cvt_pk_fp8_f32(v[q].z, v[q].w, pk, true);  // bytes 2,3
    ((unsigned int*)(dst + (row0 + q) * D_))[lane] = (unsigned int)pk;
  }
  part[w][lane] = s4;
  if (lane == 0) nred[w] = nsum;
  __syncthreads();
  if (tid < 64){
    f4 t = part[0][tid];
    #pragma unroll
    for (int q = 1; q < 4; q++){
      t[0] += part[q][tid][0]; t[1] += part[q][tid][1];
      t[2] += part[q][tid][2]; t[3] += part[q][tid][3];
    }
    *(f4*)(Ppart + ((size_t)s * 2048 + blockIdx.x) * 256 + tid * 4) = t;
  }
  if (tid == 0)
    npart[s * 2048 + blockIdx.x] = nred[0] + nred[1] + nred[2] + nred[3];
}

// d[b][n][m] = pn[n] + ln[m] - 2*dot via MX-SCALED FP8 MFMA; NO stores — only
// per-batch min. Round-21 resubmit #2 (R10 was a GPUAcquisitionTimeout —
// broker capacity, kernel never ran; per the no-change-on-infra-failure rule
// this is byte-identical). Basis: the R9 diagnostic (REP=2, first real gemm
// counters) showed MfmaUtil 29 + VALUBusy 27, occupancy 19%, no spills,
// conflicts minor: lockstep phase serialization + exposed pn L2 latency,
// per-step fixed overhead ~4400 cyc vs 2200 MFMA. Fixes, geometry untouched:
// (1) 4 steps of 256-row stripes (was 8x128) — per-step fixed cost paid half
//     as often; As dbuf's 2nd buffer ALIASES the dead Bs region (Bs only
//     feeds the bfr reg-cache; aliasing validated R7/R8). LDS 64+64+4 KB.
// (2) pn staged once into pnL (LDS) — kills ~300cyc/step epilogue L2 stall.
// (3) per-i MFMA grouping with epilogue(i-1) interleaved — epilogue VALU
//     co-issues with the next group's MFMA stream (m114 separate pipes).
// Barriers 10 -> 5. acc[4][2] goes to AGPRs (R9: VGPR_Count=112 proves acc
// is accum-allocated). Staging, XOR r&7 chunk swizzle, 32x32x64 MX fragments,
// C/D col=lane&31 row=(reg&3)+8*(reg>>2)+4*half: byte-identical. gemm feeds
// ONLY dmin's skip certificate (guard 16 covers fp8 quant error).
__global__ __launch_bounds__(512, 2) void gemm_minmax(
    const unsigned char* __restrict__ pa, const unsigned char* __restrict__ pbm,
    const float* __restrict__ pn, const float* __restrict__ ln,
    int* __restrict__ dmin)
{
  int lid = blockIdx.x;              // 256 blocks, round-robin over 8 XCDs
  int xcd = lid & 7;
  int l = lid >> 3;                  // 0..31 sequential per XCD
  int b = 2 * xcd + (l >> 4);        // 2 batches per XCD
  int p = l & 15;                    // 8 tn-panels x 2 tm-halves
  int tn = (p & 7) * 256;
  int tmb = (p >> 3) * 1024;         // 4 stripes of 256 rows each
  const unsigned char* A  = pa  + (size_t)b * N_ * D_;
  const unsigned char* Bm = pbm + (size_t)b * N_ * D_;
  // LDS: [0,64K) = Bs (prologue) then As buf1 (Bs dead after bfr cache);
  //      [64K,128K) = As buf0; [128K,132K) = pnL (1024 f32).
  __shared__ __align__(16) unsigned char smem[135168];
  __shared__ float minred[8];
  unsigned char* Bs   = smem;
  unsigned char* bufA = smem + 65536;   // stripe 0,2
  unsigned char* bufB = smem;           // stripe 1,3 (aliases Bs)
  float* pnL = (float*)(smem + 131072);
  int tid = threadIdx.x, lane = tid & 63, w = tid >> 6;
  int wm2 = (w >> 2) * 128, wn = (w & 3) * 64;  // 2m x 4n waves; 128x64 wave tile
  int l31 = lane & 31, half = lane >> 5;
  int rB = lane >> 4, cB = lane & 15;
  const int SC = 0x7F7F7F7F;         // e8m0 scale 1.0 in every byte

  // ---- prologue: stage Bs (256x256B), A stripe 0 (256x256B), pnL (4KB) ----
  #pragma unroll
  for (int q = 0; q < 8; q++){
    int R = q * 32 + w * 4;
    int r = R + rB;
    int gc = cB ^ (r & 7);           // global-side XOR swizzle (involution)
    __builtin_amdgcn_global_load_lds(
        (const AS1 unsigned int*)(const void*)&Bm[(size_t)(tn + r) * D_ + gc * 16],
        (AS3 unsigned int*)(void*)&Bs[R * 256 + lane * 16], 16, 0, 0);
    __builtin_amdgcn_global_load_lds(
        (const AS1 unsigned int*)(const void*)&A[(size_t)(tmb + r) * D_ + gc * 16],
        (AS3 unsigned int*)(void*)&bufA[R * 256 + lane * 16], 16, 0, 0);
  }
  #pragma unroll
  for (int q = 0; q < 2; q++){
    __builtin_amdgcn_global_load_lds(
        (const AS1 unsigned int*)(const void*)&pn[(size_t)b * N_ + tmb + q * 512 + tid],
        (AS3 unsigned int*)(void*)&pnL[q * 512 + w * 64], 4, 0, 0);
  }

  float lnj[2];
  #pragma unroll
  for (int j = 0; j < 2; j++)
    lnj[j] = ln[(size_t)b * N_ + tn + wn + j * 32 + l31];

  __syncthreads();   // Bs + stripe0 + pnL resident

  // ---- full-K B fragment cache: 16 x ds_read_b128 -> regs, read once ----
  v8i bfr[2][4];
  #pragma unroll
  for (int j = 0; j < 2; j++){
    int rb = wn + j * 32 + l31;
    #pragma unroll
    for (int kc = 0; kc < 4; kc++){
      int c0 = kc * 4 + half * 2;
      int4 lo = *(const int4*)&Bs[rb * 256 + ((c0 ^ (rb & 7)) * 16)];
      int4 hi = *(const int4*)&Bs[rb * 256 + (((c0 + 1) ^ (rb & 7)) * 16)];
      v8i t;
      t[0] = lo.x; t[1] = lo.y; t[2] = lo.z; t[3] = lo.w;
      t[4] = hi.x; t[5] = hi.y; t[6] = hi.z; t[7] = hi.w;
      bfr[j][kc] = t;
    }
  }

  float mind = 3.4e38f;
  for (int t = 0; t < 4; t++){       // 4 stripes of 256 rows, full-K each
    // barrier: (t=0) all waves done reading Bs -> bufB may be overwritten;
    // (t>0) drains last step's staging + WAR on the buffer we now overwrite.
    __syncthreads();
    const unsigned char* Acur = (t & 1) ? bufB : bufA;
    unsigned char* Anxt = (t & 1) ? bufA : bufB;
    if (t < 3){
      #pragma unroll
      for (int q = 0; q < 8; q++){
        int R = q * 32 + w * 4;
        int r = R + rB;
        int gc = cB ^ (r & 7);
        __builtin_amdgcn_global_load_lds(
            (const AS1 unsigned int*)(const void*)&A[(size_t)(tmb + (t + 1) * 256 + r) * D_ + gc * 16],
            (AS3 unsigned int*)(void*)&Anxt[R * 256 + lane * 16], 16, 0, 0);
      }
    }

    f16v acc[4][2];
    #pragma unroll
    for (int i = 0; i < 4; i++){ acc[i][0] = (f16v)0.f; acc[i][1] = (f16v)0.f; }

    int pbase = t * 256 + wm2;
    // per-i groups: MFMA(i) stream; epilogue(i-1) interleaves on the VALU pipe.
    #pragma unroll
    for (int i = 0; i < 4; i++){
      int ra = wm2 + i * 32 + l31;
      v8i af[4];
      #pragma unroll
      for (int kc = 0; kc < 4; kc++){
        int c0 = kc * 4 + half * 2;
        int4 lo = *(const int4*)&Acur[ra * 256 + ((c0 ^ (ra & 7)) * 16)];
        int4 hi = *(const int4*)&Acur[ra * 256 + (((c0 + 1) ^ (ra & 7)) * 16)];
        v8i tt;
        tt[0] = lo.x; tt[1] = lo.y; tt[2] = lo.z; tt[3] = lo.w;
        tt[4] = hi.x; tt[5] = hi.y; tt[6] = hi.z; tt[7] = hi.w;
        af[kc] = tt;
      }
      #pragma unroll
      for (int kc = 0; kc < 4; kc++){
        acc[i][0] = __builtin_amdgcn_mfma_scale_f32_32x32x64_f8f6f4(
            af[kc], bfr[0][kc], acc[i][0], 0, 0, 0, SC, 0, SC);
        acc[i][1] = __builtin_amdgcn_mfma_scale_f32_32x32x64_f8f6f4(
            af[kc], bfr[1][kc], acc[i][1], 0, 0, 0, SC, 0, SC);
      }
      if (i > 0){
        int ip = i - 1;
        float4 pnq[4];
        #pragma unroll
        for (int q = 0; q < 4; q++)
          pnq[q] = *(const float4*)&pnL[pbase + ip * 32 + half * 4 + q * 8];
        #pragma unroll
        for (int j = 0; j < 2; j++){
          #pragma unroll
          for (int reg = 0; reg < 16; reg += 2){
            float pl0 = ((const float*)&pnq[reg >> 2])[reg & 3] + lnj[j];
            float pl1 = ((const float*)&pnq[reg >> 2])[(reg & 3) + 1] + lnj[j];
            float v0 = fmaf(-2.f, acc[ip][j][reg], pl0);
            float v1 = fmaf(-2.f, acc[ip][j][reg + 1], pl1);
            mind = fminf(mind, fminf(v0, v1));
          }
        }
      }
    }
    {   // epilogue of the last group
      int ip = 3;
      float4 pnq[4];
      #pragma unroll
      for (int q = 0; q < 4; q++)
        pnq[q] = *(const float4*)&pnL[pbase + ip * 32 + half * 4 + q * 8];
      #pragma unroll
      for (int j = 0; j < 2; j++){
        #pragma unroll
        for (int reg = 0; reg < 16; reg += 2){
          float pl0 = ((const float*)&pnq[reg >> 2])[reg & 3] + lnj[j];
          float pl1 = ((const float*)&pnq[reg >> 2])[(reg & 3) + 1] + lnj[j];
          float v0 = fmaf(-2.f, acc[ip][j][reg], pl0);
          float v1 = fmaf(-2.f, acc[ip][j][reg + 1], pl1);
          mind = fminf(mind, fminf(v0, v1));
        }
      }
    }
  }

  #pragma unroll
  for (int off = 32; off >= 1; off >>= 1) mind = fminf(mind, __shfl_xor(mind, off));
  if (lane == 0) minred[w] = mind;
  __syncthreads();
  if (tid == 0){
    float m = minred[0];
    #pragma unroll
    for (int q = 1; q < 8; q++) m = fminf(m, minred[q]);
    atomicMin(&dmin[b], __float_as_int(fmaxf(m, 0.f)));
  }
}

// Merged tail: (1) exact fallback for the 6 negative exp-factors (each skipped
// when provably negligible: B*N^2*dmax*e^{ef*dmin}/EPS < 1e-3 iff
// ef*(dmin-16) < -55; guard 16 covers fp8 dot quantization error, |err|<~8
// at 5-sigma over 4M pairs; gating monotone — if ef=-0.25 skips, all skip);
// (2) the ef=0 term. FAST PATH (all skipped -> cost == currency == 1 exactly):
// alpha = 1/2048 exactly, bw = 1, term = sum|p|^2 + sum|l|^2 - (sum p).(sum l)/1024
// from prep's fp32 partials. SLOW PATH (dead here): exact from fp32 originals.
__global__ __launch_bounds__(256) void tail(
    const float* __restrict__ preds, const float* __restrict__ labels,
    const float* __restrict__ pn, const float* __restrict__ ln,
    float* __restrict__ cost, float* __restrict__ currency,
    const int* __restrict__ dmin, const float* __restrict__ Ppart,
    const float* __restrict__ npart, float* __restrict__ out)
{
  const float EF[6] = {-256.f, -64.f, -16.f, -4.f, -1.f, -0.25f};
  int b = blockIdx.x, tid = threadIdx.x;
  float dm = __int_as_float(dmin[b]);
  __shared__ float red[256];

  if (-0.25f * (dm - 16.f) < -55.f){
    // ---- fast path: all 6 negative iterations certified negligible ----
    float Pc = 0.f, Lc = 0.f;
    for (int k = 0; k < 128; k++){
      Pc += Ppart[((size_t)b * 128 + k) * 256 + tid];
      Lc += Ppart[((size_t)(2048 + b * 128 + k)) * 256 + tid];
    }
    float np = (tid < 128) ? npart[b * 128 + tid] : 0.f;
    float nl = (tid < 128) ? npart[2048 + b * 128 + tid] : 0.f;
    float Spn = blockReduceSum(np, red);
    float Sln = blockReduceSum(nl, red);
    float dot = blockReduceSum(Pc * Lc, red);
    if (tid == 0) atomicAdd(out, Spn + Sln - dot * (1.f / 1024.f));
    return;
  }

  // ---- slow exact path from fp32 originals (not expected to execute) ----
  __shared__ float alpha_l[N_];
  __shared__ float prow[D_];
  const float* A  = preds  + (size_t)b * N_ * D_;
  const float* Bm = labels + (size_t)b * N_ * D_;
  const float* pnb = pn + (size_t)b * N_;
  const float* lnb = ln + (size_t)b * N_;
  float* costb = cost + (size_t)b * N_;
  float* curb  = currency + (size_t)b * N_;
  for (int it = 0; it < 6; it++){
    float ef = EF[it];
    if (ef * (dm - 16.f) < -55.f) continue;
    float cost_c[8], colsum_c[8], bw_c[8], costnew_c[8];
    #pragma unroll
    for (int j = 0; j < 8; j++){ cost_c[j] = costb[j*256+tid]; colsum_c[j] = 0.f; }
    for (int r = 0; r < N_; r++){
      prow[tid] = A[(size_t)r * D_ + tid];
      __syncthreads();
      float s_c[8], rs = 0.f;
      for (int j = 0; j < 8; j++){
        int m = j*256+tid; float dot = 0.f;
        for (int k = 0; k < D_; k++) dot += prow[k] * Bm[(size_t)m * D_ + k];
        float d = pnb[r] + lnb[m] - 2.f*dot;
        float s = __expf(ef * d) * cost_c[j];
        s_c[j] = s; rs += s;
      }
      float tot = blockReduceSum(rs, red);
      float a = curb[r] / (tot + EPS_);
      if (tid == 0) alpha_l[r] = a;
      #pragma unroll
      for (int j = 0; j < 8; j++) colsum_c[j] += s_c[j] * a;
      __syncthreads();
    }
    #pragma unroll
    for (int j = 0; j < 8; j++){
      float cs = colsum_c[j];
      float bw = fminf(cost_c[j] / (cs + EPS_), 1.f);
      bw_c[j] = bw; costnew_c[j] = fmaxf(cost_c[j] - bw*cs, 0.f);
    }
    float contrib = 0.f;
    for (int r = 0; r < N_; r++){
      prow[tid] = A[(size_t)r * D_ + tid];
      __syncthreads();
      float a = alpha_l[r], rbs = 0.f;
      for (int j = 0; j < 8; j++){
        int m = j*256+tid; float dot = 0.f;
        for (int k = 0; k < D_; k++) dot += prow[k] * Bm[(size_t)m * D_ + k];
        float d = pnb[r] + lnb[m] - 2.f*dot;
        float bid = __expf(ef * d) * cost_c[j] * a * bw_c[j];
        rbs += bid; contrib += bid * d;
      }
      float tot = blockReduceSum(rbs, red);
      if (tid == 0) curb[r] = fmaxf(curb[r] - tot, 0.f);
      __syncthreads();
    }
    #pragma unroll
    for (int j = 0; j < 8; j++) costb[j*256+tid] = costnew_c[j];
    float ctot = blockReduceSum(contrib, red);
    if (tid == 0) atomicAdd(out, ctot);
    __syncthreads();
  }
  // ef=0 closed form with the general state (exact):
  float s = 0.f;
  #pragma unroll
  for (int j = 0; j < 8; j++) s += costb[j*256+tid];
  float Sc = blockReduceSum(s, red);
  float sa = 0.f, spn = 0.f;
  #pragma unroll
  for (int j = 0; j < 8; j++){
    int i = j*256+tid;
    float a = curb[i] / (Sc + EPS_);
    alpha_l[i] = a; sa += a; spn += a * pnb[i];
  }
  float Sa  = blockReduceSum(sa, red);
  float Spn = blockReduceSum(spn, red);
  float Pc = 0.f;
  for (int r = 0; r < N_; r++)
    Pc += alpha_l[r] * A[(size_t)r * D_ + tid];
  __syncthreads();
  float sv = 0.f, sln = 0.f;
  #pragma unroll
  for (int j = 0; j < 8; j++){
    int i = j*256+tid;
    float c = costb[i];
    float bw = fminf(c / (c * Sa + EPS_), 1.f);
    float vv = c * bw;
    alpha_l[i] = vv; sv += vv; sln += vv * lnb[i];
  }
  float Sv  = blockReduceSum(sv, red);
  float Sln = blockReduceSum(sln, red);
  float Lc = 0.f;
  for (int m = 0; m < N_; m++)
    Lc += alpha_l[m] * Bm[(size_t)m * D_ + tid];
  float dot = blockReduceSum(Pc * Lc, red);
  if (tid == 0) atomicAdd(out, Spn * Sv + Sa * Sln - 2.f * dot);
}

extern "C" void kernel_launch(void* const* d_in, const int* in_sizes, int n_in,
                              void* d_out, int out_size, void* d_ws, size_t ws_size,
                              hipStream_t stream)
{
  const float* preds  = (const float*)d_in[0];
  const float* labels = (const float*)d_in[1];
  float* out = (float*)d_out;
  char* ws = (char*)d_ws;
  const size_t BN = (size_t)B_ * N_;
  size_t off = 0;
  float* cost     = (float*)(ws + off); off += BN * 4;
  float* currency = (float*)(ws + off); off += BN * 4;
  float* pn       = (float*)(ws + off); off += BN * 4;
  float* ln       = (float*)(ws + off); off += BN * 4;
  int*   dmin     = (int*)(ws + off);   off += 256;
  float* npart    = (float*)(ws + off); off += (size_t)2 * 2048 * 4;
  float* Ppart    = (float*)(ws + off); off += (size_t)2 * 2048 * 256 * 4;
  unsigned char* pa8 = (unsigned char*)(ws + off); off += BN * D_;
  unsigned char* pb8 = (unsigned char*)(ws + off); off += BN * D_;

  prep_kernel<<<dim3((unsigned)(BN / 16), 2), 256, 0, stream>>>(
      preds, labels, pa8, pb8, pn, ln, cost, currency, dmin, Ppart, npart, out);
  gemm_minmax<<<dim3(256), 512, 0, stream>>>(pa8, pb8, pn, ln, dmin);
  tail<<<dim3(B_), 256, 0, stream>>>(preds, labels, pn, ln, cost, currency, dmin,
                                     Ppart, npart, out);
}